// Round 5
// baseline (93.518 us; speedup 1.0000x reference)
//
#include <hip/hip_runtime.h>
#include <hip/hip_bf16.h>

#define N_F 100
#define N_B 4096
#define DH 96
#define DT 192
#define BW 16      // b-rows per wave (= per 64-thread workgroup)
#define SPAD 100   // stage row stride in floats (96 + 4)

typedef unsigned short u16;
typedef unsigned int u32;
typedef __bf16 bf16x8 __attribute__((ext_vector_type(8)));
typedef float f32x4 __attribute__((ext_vector_type(4)));

union FragAB { bf16x8 v; uint2 q2[2]; uint4 q4; };

static __device__ __forceinline__ u16 f2bf(float v) {
    u32 b = __float_as_uint(v);
    return (u16)((b + 0x7FFFu + ((b >> 16) & 1u)) >> 16);  // RNE, no NaN in data
}

// tanh-form gelu: max abs deviation from exact erf-gelu ~3e-4 (<< bf16 rounding of h)
static __device__ __forceinline__ float gelu_fast(float p) {
    float p3 = p * p * p;
    float y  = fmaf(0.044715f, p3, p);
    float t  = exp2f(2.3022083f * y);
    float r  = __builtin_amdgcn_rcpf(1.0f + t);
    return fmaf(-p, r, p);                     // p - p/(1+t)
}

// W2[f][k][d] (f32) -> MFMA-fragment-ordered bf16 W2F.
// W2F[((ks*12 + DT16)*64 + q*16 + m)*8 + e]
//   d = DT16*16 + m ; k = ks*32 + (e>>2)*16 + q*4 + (e&3)
__global__ void convert_w2_kernel(const float* __restrict__ W2, u16* __restrict__ W2F) {
    int idx = blockIdx.x * 256 + threadIdx.x;          // over N_F*DH*(DT/4)
    if (idx >= N_F * DH * (DT / 4)) return;
    int f  = idx / (DH * (DT / 4));
    int r  = idx - f * (DH * (DT / 4));
    int k  = r / (DT / 4);
    int d4 = (r - k * (DT / 4)) * 4;
    const float4 w = *(const float4*)&W2[(f * DH + k) * DT + d4];

    int ks = k >> 5;
    int kr = k & 31;
    int q  = (kr >> 2) & 3;
    int e  = ((kr >> 4) << 2) | (kr & 3);
    u16* base = W2F + (size_t)f * (DH * DT);
    int DT16 = d4 >> 4;
    int m    = d4 & 15;
    size_t i0 = ((size_t)(ks * 12 + DT16) * 64 + q * 16 + m) * 8 + e;
    base[i0]      = f2bf(w.x);
    base[i0 + 8]  = f2bf(w.y);
    base[i0 + 16] = f2bf(w.z);
    base[i0 + 24] = f2bf(w.w);
}

// Barrier-free: one wave per workgroup owns 16 b-rows x all 192 d.
// gelu -> B-frags in registers (no h LDS, no syncthreads); wave-private
// ping-pong epilogue stage (intra-wave lgkmcnt only); linear 1KB stores.
template <bool USE_WS>
__global__ __launch_bounds__(64, 3) void mlp_tok_kernel(
    const float* __restrict__ x, const float* __restrict__ W1,
    const float* __restrict__ b1, const float* __restrict__ W2,
    const float* __restrict__ b2, const u16* __restrict__ W2F,
    float* __restrict__ out)
{
    const int f    = blockIdx.x;          // f fastest: concurrent wgs share b-window
    const int b0   = blockIdx.y * BW;
    const int lane = threadIdx.x;         // 0..63
    const int q    = lane >> 4;
    const int m    = lane & 15;

    __shared__ float stage[2][BW][SPAD];  // 12.8 KB, wave-private (1 wave/wg)

    const float xv = x[(size_t)(b0 + m) * N_F + f];

    // ---- Phase 1: 24 gelu straight into B-fragments.
    // frag elem j(0..3) <-> k = k0+j, elem j(4..7) <-> k = k0+16+j (k0 = ks*32+q*4)
    FragAB hb[3];
    #pragma unroll
    for (int ks = 0; ks < 3; ++ks) {
        #pragma unroll
        for (int hh = 0; hh < 2; ++hh) {
            const int k0 = ks * 32 + hh * 16 + q * 4;
            const float4 w1v = *(const float4*)&W1[f * DH + k0];
            const float4 b1v = *(const float4*)&b1[f * DH + k0];
            float g0 = gelu_fast(fmaf(xv, w1v.x, b1v.x));
            float g1 = gelu_fast(fmaf(xv, w1v.y, b1v.y));
            float g2 = gelu_fast(fmaf(xv, w1v.z, b1v.z));
            float g3 = gelu_fast(fmaf(xv, w1v.w, b1v.w));
            uint2 pk;
            pk.x = (u32)f2bf(g0) | ((u32)f2bf(g1) << 16);
            pk.y = (u32)f2bf(g2) | ((u32)f2bf(g3) << 16);
            hb[ks].q2[hh] = pk;
        }
    }

    // ---- Phase 2: A = W2 (rows=d), B = h^T (cols=b). D: row=d=4q+reg, col=b=m.
    f32x4 acc[12];
    #pragma unroll
    for (int dt = 0; dt < 12; ++dt) acc[dt] = (f32x4){0.f, 0.f, 0.f, 0.f};

    const u16* __restrict__ w2ff = USE_WS ? (W2F + (size_t)f * (DH * DT)) : nullptr;

    #pragma unroll
    for (int ks = 0; ks < 3; ++ks) {
        FragAB a[12];
        #pragma unroll
        for (int dt = 0; dt < 12; ++dt) {
            if constexpr (USE_WS) {
                a[dt].q4 = *(const uint4*)&w2ff[((size_t)(ks * 12 + dt) * 64 + lane) * 8];
            } else {
                const int d = dt * 16 + m;
                u16 tmp[8];
                #pragma unroll
                for (int e = 0; e < 8; ++e) {
                    const int k = ks * 32 + (e >> 2) * 16 + q * 4 + (e & 3);
                    tmp[e] = f2bf(W2[((size_t)f * DH + k) * DT + d]);
                }
                a[dt].q4 = make_uint4(
                    (u32)tmp[0] | ((u32)tmp[1] << 16), (u32)tmp[2] | ((u32)tmp[3] << 16),
                    (u32)tmp[4] | ((u32)tmp[5] << 16), (u32)tmp[6] | ((u32)tmp[7] << 16));
            }
        }
        #pragma unroll
        for (int dt = 0; dt < 12; ++dt)
            acc[dt] = __builtin_amdgcn_mfma_f32_16x16x32_bf16(
                a[dt].v, hb[ks].v, acc[dt], 0, 0, 0);
    }

    // ---- Epilogue: two d-halves, ping-pong stage, no s_barrier ever.
    #pragma unroll
    for (int h = 0; h < 2; ++h) {
        #pragma unroll
        for (int dtl = 0; dtl < 6; ++dtl) {
            const int dt = h * 6 + dtl;
            const f32x4 bq = *(const f32x4*)&b2[f * DT + dt * 16 + q * 4];
            f32x4 v = acc[dt] + bq;
            *(f32x4*)&stage[h][m][dtl * 16 + q * 4] = v;
        }
        // intra-wave LDS visibility: wait LDS ops only (global stores unaffected)
        asm volatile("s_waitcnt lgkmcnt(0)" ::: "memory");
        __builtin_amdgcn_sched_barrier(0);
        #pragma unroll
        for (int i = 0; i < 6; ++i) {
            const int idx = i * 64 + lane;         // 16 rows x 24 float4 slots
            const int row = idx / 24;
            const int c4  = idx - row * 24;
            f32x4 v = *(const f32x4*)&stage[h][row][c4 * 4];
            *(f32x4*)&out[((size_t)(b0 + row) * N_F + f) * DT + h * 96 + c4 * 4] = v;
        }
    }
}

extern "C" void kernel_launch(void* const* d_in, const int* in_sizes, int n_in,
                              void* d_out, int out_size, void* d_ws, size_t ws_size,
                              hipStream_t stream) {
    const float* x  = (const float*)d_in[0];
    const float* W1 = (const float*)d_in[1];
    const float* b1 = (const float*)d_in[2];
    const float* W2 = (const float*)d_in[3];
    const float* b2 = (const float*)d_in[4];
    float* out = (float*)d_out;

    const size_t w2f_bytes = (size_t)N_F * DT * DH * sizeof(u16);
    dim3 grid(N_F, N_B / BW);   // f fastest-varying

    if (ws_size >= w2f_bytes) {
        u16* W2F = (u16*)d_ws;
        convert_w2_kernel<<<(N_F * DH * (DT / 4) + 255) / 256, 256, 0, stream>>>(W2, W2F);
        mlp_tok_kernel<true><<<grid, 64, 0, stream>>>(x, W1, b1, W2, b2, W2F, out);
    } else {
        mlp_tok_kernel<false><<<grid, 64, 0, stream>>>(x, W1, b1, W2, b2, nullptr, out);
    }
}